// Round 3
// baseline (860.843 us; speedup 1.0000x reference)
//
#include <hip/hip_runtime.h>
#include <hip/hip_bf16.h>
#include <cstdint>

// Problem constants
#define BB 4
#define TT 2048
#define EE 1024
#define HH 16
#define DD 64
#define BH (BB*HH)       // 64
#define MM (BB*TT)       // 8192 rows for projection GEMMs
#define KK 1024          // contraction dim for projections

typedef __attribute__((ext_vector_type(8))) short short8;   // 8 x bf16 (4 VGPRs)
typedef __attribute__((ext_vector_type(4))) float float4_;  // MFMA accumulator

__device__ __forceinline__ void gl_lds16(const void* g, void* l) {
    __builtin_amdgcn_global_load_lds(
        (const __attribute__((address_space(1))) void*)g,
        (__attribute__((address_space(3))) void*)l, 16, 0, 0);
}

__device__ __forceinline__ ushort f2bf(float v) {
    __hip_bfloat16 h = __float2bfloat16(v);
    return *(ushort*)&h;
}
__device__ __forceinline__ float bf2f(ushort u) {
    __hip_bfloat16 h = *(__hip_bfloat16*)&u;
    return __bfloat162float(h);
}

__device__ __forceinline__ short8 ld8_cvt_f32(const float* p) {
    short8 o;
#pragma unroll
    for (int j = 0; j < 8; j++) o[j] = (short)f2bf(p[j]);
    return o;
}

// ---------------------------------------------------------------------------
// Dtype sniff: decide whether inputs are fp32 (flag=1) or packed bf16 (flag=0).
// For bf16 data, EVEN-indexed ushorts are bf16 values of ~N(0,1) samples:
// exponent in ~[100,135]. For fp32 data, even ushorts are low mantissa bits:
// exponent field ~uniform[0,255] -> only ~20% land in [90,140].
// ---------------------------------------------------------------------------
__global__ void sniff_kernel(const void* q, int* flag) {
    const ushort* u = (const ushort*)q;
    int tid = threadIdx.x;             // 0..63
    int good = 0;
#pragma unroll
    for (int i = 0; i < 16; i++) {
        ushort v = u[(i * 64 + tid) * 2];       // even indices only
        int e = (v >> 7) & 0xFF;
        if (e >= 90 && e <= 140) good++;
    }
    for (int m = 1; m < 64; m <<= 1) good += __shfl_xor(good, m);
    if (tid == 0) *flag = (good < 700) ? 1 : 0;   // <700/1024 plausible => fp32
}

// ---------------------------------------------------------------------------
// NT GEMM: C[n,e] = sum_k A[n,k]*W[e,k] + bias[e]
// A: [MM, KK].  W: [1024, KK].  Operand dtype: bf16, or fp32 if (xF && *flag).
// mode 0: C row-major [MM, EE] (fp32 iff oF && *flag)
// mode 1: scatter to per-head layout [B*H, T, D] bf16
// 128x128 tile, BK=32, 256 threads (4 waves, 2x2 of 64x64).  (m97 structure)
// ---------------------------------------------------------------------------
__global__ __launch_bounds__(256, 2) void gemm_nt_kernel(
    const void* __restrict__ A, const void* __restrict__ W,
    const void* __restrict__ bias, void* __restrict__ Cout,
    const int* __restrict__ flag, int aF, int wF, int oF, int mode)
{
    __shared__ __align__(16) ushort As[128*32];
    __shared__ __align__(16) ushort Bs[128*32];

    const int f32 = *flag;
    const bool a32 = aF && f32;
    const bool w32 = wF && f32;

    const int tid  = threadIdx.x;
    const int wave = tid >> 6;
    const int lane = tid & 63;
    const int l15  = lane & 15;
    const int quad = lane >> 4;
    const int wm   = wave & 1;   // row half
    const int wn   = wave >> 1;  // col half

    const long rowBase = (long)blockIdx.y * 128;
    const long colBase = (long)blockIdx.x * 128;

    const ushort* Ab = (const ushort*)A;
    const ushort* Wb = (const ushort*)W;
    const float*  Af = (const float*)A;
    const float*  Wf = (const float*)W;

    float4_ acc[4][4];
#pragma unroll
    for (int i = 0; i < 4; i++)
#pragma unroll
        for (int j = 0; j < 4; j++) acc[i][j] = float4_{0.f, 0.f, 0.f, 0.f};

    for (int k0 = 0; k0 < KK; k0 += 32) {
        __syncthreads();
#pragma unroll
        for (int it = 0; it < 2; it++) {
            int idx = it * 256 + tid;          // 0..511
            int r   = idx >> 2;                // tile row 0..127
            int c8  = (idx & 3) * 8;           // k chunk (8 elems)
            if (!a32) gl_lds16(Ab + (rowBase + r) * KK + k0 + c8, &As[idx * 8]);
            else *(short8*)&As[idx * 8] = ld8_cvt_f32(Af + (rowBase + r) * KK + k0 + c8);
            if (!w32) gl_lds16(Wb + (colBase + r) * KK + k0 + c8, &Bs[idx * 8]);
            else *(short8*)&Bs[idx * 8] = ld8_cvt_f32(Wf + (colBase + r) * KK + k0 + c8);
        }
        __syncthreads();

        short8 af[4], bf[4];
#pragma unroll
        for (int mt = 0; mt < 4; mt++)
            af[mt] = *(const short8*)&As[(wm*64 + mt*16 + l15) * 32 + quad*8];
#pragma unroll
        for (int nt = 0; nt < 4; nt++)
            bf[nt] = *(const short8*)&Bs[(wn*64 + nt*16 + l15) * 32 + quad*8];
#pragma unroll
        for (int mt = 0; mt < 4; mt++)
#pragma unroll
            for (int nt = 0; nt < 4; nt++)
                acc[mt][nt] = __builtin_amdgcn_mfma_f32_16x16x32_bf16(
                    af[mt], bf[nt], acc[mt][nt], 0, 0, 0);
    }

    // Epilogue: C/D layout col = lane&15, row = quad*4 + reg
#pragma unroll
    for (int nt = 0; nt < 4; nt++) {
        const long col = colBase + wn*64 + nt*16 + l15;
        const float bv = w32 ? ((const float*)bias)[col] : bf2f(((const ushort*)bias)[col]);
#pragma unroll
        for (int mt = 0; mt < 4; mt++) {
#pragma unroll
            for (int i = 0; i < 4; i++) {
                const long row = rowBase + wm*64 + mt*16 + quad*4 + i;
                const float v = acc[mt][nt][i] + bv;
                if (mode == 0) {
                    if (oF && f32) ((float*)Cout)[row * EE + col] = v;
                    else           ((ushort*)Cout)[row * EE + col] = f2bf(v);
                } else {
                    const long b = row >> 11, t = row & (TT - 1);
                    const long h = col >> 6,  d = col & (DD - 1);
                    ((ushort*)Cout)[(((b*HH + h) * TT) + t) * DD + d] = f2bf(v);
                }
            }
        }
    }
}

// ---------------------------------------------------------------------------
// Flash attention (causal). Q,K,V: [B*H, T, D] bf16 (workspace); AO: [B,T,E] bf16.
// Block: 64 q-rows (wave w owns rows w*16..w*16+15), loops over 64-key tiles.
// ---------------------------------------------------------------------------
__global__ __launch_bounds__(256, 2) void flash_kernel(
    const ushort* __restrict__ Qh, const ushort* __restrict__ Kh,
    const ushort* __restrict__ Vh, ushort* __restrict__ AO)
{
    __shared__ __align__(16) ushort Ks[64*64];     // [key][d]
    __shared__ __align__(16) ushort Vs[64*64];     // [d][key]  (transposed)
    __shared__ __align__(16) ushort Ps[4][16*64];  // per-wave P tile [q][key]

    const int qt  = blockIdx.x;        // q tile (64 rows)
    const int bh  = blockIdx.y;        // b*H + h
    const int tid = threadIdx.x;
    const int wave = tid >> 6, lane = tid & 63;
    const int l15 = lane & 15, quad = lane >> 4;

    const ushort* Qb = Qh + (long)bh * TT * DD;
    const ushort* Kb = Kh + (long)bh * TT * DD;
    const ushort* Vb = Vh + (long)bh * TT * DD;

    // Q A-fragments (A[m=lane&15][k=quad*8+j]), kept in registers
    const int qrowA = qt*64 + wave*16 + l15;
    short8 aq0 = *(const short8*)&Qb[(long)qrowA * DD + quad*8];
    short8 aq1 = *(const short8*)&Qb[(long)qrowA * DD + 32 + quad*8];

    float4_ o[4];
#pragma unroll
    for (int nt = 0; nt < 4; nt++) o[nt] = float4_{0.f, 0.f, 0.f, 0.f};
    float m_run[4], l_run[4];
#pragma unroll
    for (int i = 0; i < 4; i++) { m_run[i] = -INFINITY; l_run[i] = 0.0f; }

    ushort* pw = &Ps[wave][0];

    for (int kt = 0; kt <= qt; kt++) {
        __syncthreads();   // previous tile's LDS reads done
        // stage K tile [key][d] and V tile transposed [d][key]
#pragma unroll
        for (int it = 0; it < 2; it++) {
            int idx = it * 256 + tid;   // 0..511
            int r = idx >> 3;           // key 0..63
            int c = (idx & 7) * 8;      // d chunk
            short8 kv = *(const short8*)&Kb[((long)(kt*64 + r)) * DD + c];
            short8 vv = *(const short8*)&Vb[((long)(kt*64 + r)) * DD + c];
            *(short8*)&Ks[r*64 + c] = kv;
#pragma unroll
            for (int j = 0; j < 8; j++) Vs[(c + j) * 64 + r] = ((ushort*)&vv)[j];
        }
        __syncthreads();

        // S = Q K^T * scale   (C layout: row=quad*4+i, col=l15 within nt tile)
        float4_ s[4];
#pragma unroll
        for (int nt = 0; nt < 4; nt++) s[nt] = float4_{0.f, 0.f, 0.f, 0.f};
#pragma unroll
        for (int nt = 0; nt < 4; nt++) {
            short8 bk0 = *(const short8*)&Ks[(nt*16 + l15) * 64 + quad*8];
            short8 bk1 = *(const short8*)&Ks[(nt*16 + l15) * 64 + 32 + quad*8];
            s[nt] = __builtin_amdgcn_mfma_f32_16x16x32_bf16(aq0, bk0, s[nt], 0,0,0);
            s[nt] = __builtin_amdgcn_mfma_f32_16x16x32_bf16(aq1, bk1, s[nt], 0,0,0);
        }
        const bool diag = (kt == qt);   // only the diagonal tile needs masking
#pragma unroll
        for (int nt = 0; nt < 4; nt++) {
            const int key = kt*64 + nt*16 + l15;
#pragma unroll
            for (int i = 0; i < 4; i++) {
                float v = s[nt][i] * 0.125f;   // 1/sqrt(64)
                const int qr = qt*64 + wave*16 + quad*4 + i;
                if (diag && key > qr) v = -INFINITY;
                s[nt][i] = v;
            }
        }

        // online softmax (rows live across l15 lanes of the same quad)
        float alpha[4];
#pragma unroll
        for (int i = 0; i < 4; i++) {
            float v = fmaxf(fmaxf(s[0][i], s[1][i]), fmaxf(s[2][i], s[3][i]));
            v = fmaxf(v, __shfl_xor(v, 1));
            v = fmaxf(v, __shfl_xor(v, 2));
            v = fmaxf(v, __shfl_xor(v, 4));
            v = fmaxf(v, __shfl_xor(v, 8));
            const float mnew = fmaxf(m_run[i], v);   // always finite (>=1 unmasked key)
            alpha[i] = __expf(m_run[i] - mnew);      // 0 on first tile
            m_run[i] = mnew;
        }
        float rs[4] = {0.f, 0.f, 0.f, 0.f};
#pragma unroll
        for (int nt = 0; nt < 4; nt++) {
#pragma unroll
            for (int i = 0; i < 4; i++) {
                const float p = __expf(s[nt][i] - m_run[i]);  // masked -> 0
                s[nt][i] = p;
                rs[i] += p;
            }
        }
#pragma unroll
        for (int i = 0; i < 4; i++) {
            float v = rs[i];
            v += __shfl_xor(v, 1);
            v += __shfl_xor(v, 2);
            v += __shfl_xor(v, 4);
            v += __shfl_xor(v, 8);
            l_run[i] = l_run[i] * alpha[i] + v;
        }
#pragma unroll
        for (int nt = 0; nt < 4; nt++)
#pragma unroll
            for (int i = 0; i < 4; i++) o[nt][i] *= alpha[i];

        // P: C-layout regs -> wave-private LDS -> A-layout frags (bf16)
#pragma unroll
        for (int nt = 0; nt < 4; nt++)
#pragma unroll
            for (int i = 0; i < 4; i++)
                pw[(quad*4 + i) * 64 + nt*16 + l15] = f2bf(s[nt][i]);
        __threadfence_block();   // order LDS write -> read within the wave

        // O += P @ V   (contract over 64 keys = 2 mfma k-chunks)
#pragma unroll
        for (int c = 0; c < 2; c++) {
            short8 ap = *(const short8*)&pw[l15 * 64 + c*32 + quad*8];
#pragma unroll
            for (int nt = 0; nt < 4; nt++) {
                short8 bv = *(const short8*)&Vs[(nt*16 + l15) * 64 + c*32 + quad*8];
                o[nt] = __builtin_amdgcn_mfma_f32_16x16x32_bf16(ap, bv, o[nt], 0,0,0);
            }
        }
    }

    // epilogue: AO[b, t, h*64+d] = o / l
    const int h = bh & (HH - 1);
    const int b = bh >> 4;
#pragma unroll
    for (int nt = 0; nt < 4; nt++) {
#pragma unroll
        for (int i = 0; i < 4; i++) {
            const int t = qt*64 + wave*16 + quad*4 + i;
            const int e = h*64 + nt*16 + l15;
            AO[((long)(b*TT + t)) * EE + e] = f2bf(o[nt][i] / l_run[i]);
        }
    }
}

// ---------------------------------------------------------------------------
extern "C" void kernel_launch(void* const* d_in, const int* in_sizes, int n_in,
                              void* d_out, int out_size, void* d_ws, size_t ws_size,
                              hipStream_t stream)
{
    const void* query  = d_in[0];
    const void* key_in = d_in[1];
    const void* value  = d_in[2];
    // d_in[3] = mask (int32 tril) — causal is hard-coded in flash_kernel
    const void* Wq = d_in[4];
    const void* bq = d_in[5];
    const void* Wk = d_in[6];
    const void* bk = d_in[7];
    const void* Wv = d_in[8];
    const void* bv = d_in[9];
    const void* Wo = d_in[10];
    const void* bo = d_in[11];

    int* flag = (int*)d_ws;
    ushort* ws = (ushort*)d_ws + 64;           // tensors start at +128 B
    const size_t NPH = (size_t)BH * TT * DD;   // 8388608 elems per tensor
    ushort* Qh  = ws;                          // 16 MB
    ushort* Kh  = ws + NPH;                    // 16 MB
    ushort* Vh  = ws + 2*NPH;                  // 16 MB
    ushort* AO  = ws + 3*NPH;                  // 16 MB  (total 64 MB + 128 B)

    sniff_kernel<<<1, 64, 0, stream>>>(query, flag);

    dim3 gemm_grid(EE/128, MM/128);           // 8 x 64
    gemm_nt_kernel<<<gemm_grid, 256, 0, stream>>>(query,  Wq, bq, Qh, flag, 1, 1, 0, 1);
    gemm_nt_kernel<<<gemm_grid, 256, 0, stream>>>(key_in, Wk, bk, Kh, flag, 1, 1, 0, 1);
    gemm_nt_kernel<<<gemm_grid, 256, 0, stream>>>(value,  Wv, bv, Vh, flag, 1, 1, 0, 1);
    flash_kernel<<<dim3(TT/64, BH), 256, 0, stream>>>(Qh, Kh, Vh, AO);
    gemm_nt_kernel<<<gemm_grid, 256, 0, stream>>>(AO, Wo, bo, d_out, flag, 0, 1, 1, 0);
}

// Round 4
// 613.056 us; speedup vs baseline: 1.4042x; 1.4042x over previous
//
#include <hip/hip_runtime.h>
#include <hip/hip_bf16.h>
#include <cstdint>

// Problem constants
#define BB 4
#define TT 2048
#define EE 1024
#define HH 16
#define DD 64
#define BH (BB*HH)       // 64
#define MM (BB*TT)       // 8192 rows for projection GEMMs
#define KK 1024          // contraction dim for projections
#define LSTR 72          // flash LDS row stride (ushorts): 144B, bank-balanced

typedef __attribute__((ext_vector_type(8))) short short8;    // 8 x bf16
typedef __attribute__((ext_vector_type(4))) float float4_;   // MFMA accumulator
typedef __attribute__((ext_vector_type(4))) ushort ushort4_;

__device__ __forceinline__ void gl_lds16(const void* g, void* l) {
    __builtin_amdgcn_global_load_lds(
        (const __attribute__((address_space(1))) void*)g,
        (__attribute__((address_space(3))) void*)l, 16, 0, 0);
}

__device__ __forceinline__ ushort f2bf(float v) {
    __hip_bfloat16 h = __float2bfloat16(v);
    return *(ushort*)&h;
}

// ---------------------------------------------------------------------------
// NT GEMM: C[n,e] = sum_k A[n,k]*W[e,k] + bias[e], then *scale.
// Operand dtypes compile-time: AF32/WF32 (fp32 staged to LDS via
// global_load_lds, converted to bf16 at fragment read; bf16 staged direct).
// MODE 0: C fp32 row-major [MM, EE]
// MODE 1: scatter bf16 per-head [B*H, T, D]
// MODE 2: scatter bf16 per-head transposed [B*H, D, T] (packed 8B stores)
// 128x128 tile, BK=32, 256 threads (4 waves, 2x2 of 64x64).  (m97 structure)
// ---------------------------------------------------------------------------
template<int AF32, int WF32, int MODE>
__global__ __launch_bounds__(256, 2) void gemm_nt(
    const void* __restrict__ A, const void* __restrict__ W,
    const float* __restrict__ bias, void* __restrict__ Cout, float scale)
{
    __shared__ __align__(16) unsigned char AsB[AF32 ? 128*32*4 : 128*32*2];
    __shared__ __align__(16) unsigned char BsB[WF32 ? 128*32*4 : 128*32*2];

    const int tid  = threadIdx.x;
    const int wave = tid >> 6;
    const int lane = tid & 63;
    const int l15  = lane & 15;
    const int quad = lane >> 4;
    const int wm   = wave & 1;   // row half
    const int wn   = wave >> 1;  // col half

    const long rowBase = (long)blockIdx.y * 128;
    const long colBase = (long)blockIdx.x * 128;

    float4_ acc[4][4];
#pragma unroll
    for (int i = 0; i < 4; i++)
#pragma unroll
        for (int j = 0; j < 4; j++) acc[i][j] = float4_{0.f, 0.f, 0.f, 0.f};

    for (int k0 = 0; k0 < KK; k0 += 32) {
        __syncthreads();
        // ---- stage A tile ----
        if (AF32) {
            const float* Af = (const float*)A;
            float* As = (float*)AsB;
#pragma unroll
            for (int it = 0; it < 4; it++) {
                int idx = it * 256 + tid;          // 0..1023
                int r   = idx >> 3;                // tile row
                int c4  = (idx & 7) * 4;           // float4 chunk
                gl_lds16(Af + (rowBase + r) * KK + k0 + c4, &As[idx * 4]);
            }
        } else {
            const ushort* Ab = (const ushort*)A;
            ushort* As = (ushort*)AsB;
#pragma unroll
            for (int it = 0; it < 2; it++) {
                int idx = it * 256 + tid;          // 0..511
                int r   = idx >> 2;
                int c8  = (idx & 3) * 8;
                gl_lds16(Ab + (rowBase + r) * KK + k0 + c8, &As[idx * 8]);
            }
        }
        // ---- stage W tile ----
        if (WF32) {
            const float* Wf = (const float*)W;
            float* Bs = (float*)BsB;
#pragma unroll
            for (int it = 0; it < 4; it++) {
                int idx = it * 256 + tid;
                int r   = idx >> 3;
                int c4  = (idx & 7) * 4;
                gl_lds16(Wf + (colBase + r) * KK + k0 + c4, &Bs[idx * 4]);
            }
        } else {
            const ushort* Wb = (const ushort*)W;
            ushort* Bs = (ushort*)BsB;
#pragma unroll
            for (int it = 0; it < 2; it++) {
                int idx = it * 256 + tid;
                int r   = idx >> 2;
                int c8  = (idx & 3) * 8;
                gl_lds16(Wb + (colBase + r) * KK + k0 + c8, &Bs[idx * 8]);
            }
        }
        __syncthreads();

        short8 af[4], bf[4];
#pragma unroll
        for (int mt = 0; mt < 4; mt++) {
            const int row = wm*64 + mt*16 + l15;
            if (AF32) {
                const float* ar = (const float*)AsB + row*32 + quad*8;
                float4_ a0 = *(const float4_*)ar;
                float4_ a1 = *(const float4_*)(ar + 4);
                short8 t;
#pragma unroll
                for (int j = 0; j < 4; j++) { t[j] = (short)f2bf(a0[j]); t[4+j] = (short)f2bf(a1[j]); }
                af[mt] = t;
            } else {
                af[mt] = *(const short8*)((const ushort*)AsB + row*32 + quad*8);
            }
        }
#pragma unroll
        for (int nt = 0; nt < 4; nt++) {
            const int row = wn*64 + nt*16 + l15;
            if (WF32) {
                const float* br = (const float*)BsB + row*32 + quad*8;
                float4_ b0 = *(const float4_*)br;
                float4_ b1 = *(const float4_*)(br + 4);
                short8 t;
#pragma unroll
                for (int j = 0; j < 4; j++) { t[j] = (short)f2bf(b0[j]); t[4+j] = (short)f2bf(b1[j]); }
                bf[nt] = t;
            } else {
                bf[nt] = *(const short8*)((const ushort*)BsB + row*32 + quad*8);
            }
        }
#pragma unroll
        for (int mt = 0; mt < 4; mt++)
#pragma unroll
            for (int nt = 0; nt < 4; nt++)
                acc[mt][nt] = __builtin_amdgcn_mfma_f32_16x16x32_bf16(
                    af[mt], bf[nt], acc[mt][nt], 0, 0, 0);
    }

    // Epilogue: C/D layout col = lane&15, row = quad*4 + reg
#pragma unroll
    for (int nt = 0; nt < 4; nt++) {
        const long col = colBase + wn*64 + nt*16 + l15;
        const float bv = bias[col];
#pragma unroll
        for (int mt = 0; mt < 4; mt++) {
            const long row0 = rowBase + wm*64 + mt*16 + quad*4;
            if (MODE == 2) {
                const long h = col >> 6, d = col & (DD - 1);
                const long b = row0 >> 11, t0 = row0 & (TT - 1);
                ushort4_ pk;
#pragma unroll
                for (int i = 0; i < 4; i++) pk[i] = f2bf((acc[mt][nt][i] + bv) * scale);
                *(ushort4_*)((ushort*)Cout + ((b*HH + h)*DD + d)*TT + t0) = pk;
            } else {
#pragma unroll
                for (int i = 0; i < 4; i++) {
                    const long row = row0 + i;
                    const float v = (acc[mt][nt][i] + bv) * scale;
                    if (MODE == 0) {
                        ((float*)Cout)[row * EE + col] = v;
                    } else {
                        const long b = row >> 11, t = row & (TT - 1);
                        const long h = col >> 6,  d = col & (DD - 1);
                        ((ushort*)Cout)[(((b*HH + h) * TT) + t) * DD + d] = f2bf(v);
                    }
                }
            }
        }
    }
}

// ---------------------------------------------------------------------------
// Flash attention (causal). Q,K: [B*H, T, D] bf16; Vt: [B*H, D, T] bf16;
// AO: [B, T, E] bf16.  Scale pre-folded into Q.
// Block: 64 q-rows (wave w owns rows w*16..w*16+15), loops over 64-key tiles.
// LDS rows padded to 72 ushorts (144 B): bank-balanced b128 reads/writes.
// ---------------------------------------------------------------------------
__global__ __launch_bounds__(256, 4) void flash_kernel(
    const ushort* __restrict__ Qh, const ushort* __restrict__ Kh,
    const ushort* __restrict__ Vt, ushort* __restrict__ AO)
{
    __shared__ __align__(16) ushort Ks[64*LSTR];     // [key][d]
    __shared__ __align__(16) ushort Vs[64*LSTR];     // [d][key]
    __shared__ __align__(16) ushort Ps[4][16*LSTR];  // per-wave P tile [q][key]

    const int qt  = (TT/64 - 1) - blockIdx.x;  // heavy tiles dispatch first
    const int bh  = blockIdx.y;                // b*H + h
    const int tid = threadIdx.x;
    const int wave = tid >> 6, lane = tid & 63;
    const int l15 = lane & 15, quad = lane >> 4;

    const ushort* Qb = Qh + (long)bh * TT * DD;
    const ushort* Kb = Kh + (long)bh * TT * DD;
    const ushort* Vb = Vt + (long)bh * DD * TT;

    // Q A-fragments (A[m=lane&15][k=quad*8+j]), kept in registers
    const int qrowA = qt*64 + wave*16 + l15;
    short8 aq0 = *(const short8*)&Qb[(long)qrowA * DD + quad*8];
    short8 aq1 = *(const short8*)&Qb[(long)qrowA * DD + 32 + quad*8];

    float4_ o[4];
#pragma unroll
    for (int nt = 0; nt < 4; nt++) o[nt] = float4_{0.f, 0.f, 0.f, 0.f};
    float m_run[4], l_run[4];
#pragma unroll
    for (int i = 0; i < 4; i++) { m_run[i] = -INFINITY; l_run[i] = 0.0f; }

    ushort* pw = &Ps[wave][0];

    for (int kt = 0; kt <= qt; kt++) {
        __syncthreads();   // previous tile's LDS reads done
        // stage K tile [key][d] and V^T tile [d][key] — both vectorized
#pragma unroll
        for (int it = 0; it < 2; it++) {
            int idx = it * 256 + tid;   // 0..511
            int r = idx >> 3;           // K: key 0..63 / V: d 0..63
            int c = (idx & 7) * 8;      // 16B chunk
            *(short8*)&Ks[r*LSTR + c] = *(const short8*)&Kb[((long)(kt*64 + r)) * DD + c];
            *(short8*)&Vs[r*LSTR + c] = *(const short8*)&Vb[(long)r * TT + kt*64 + c];
        }
        __syncthreads();

        // S = Q K^T   (C layout: row=quad*4+i, col=l15 within nt tile)
        float4_ s[4];
#pragma unroll
        for (int nt = 0; nt < 4; nt++) s[nt] = float4_{0.f, 0.f, 0.f, 0.f};
#pragma unroll
        for (int nt = 0; nt < 4; nt++) {
            short8 bk0 = *(const short8*)&Ks[(nt*16 + l15) * LSTR + quad*8];
            short8 bk1 = *(const short8*)&Ks[(nt*16 + l15) * LSTR + 32 + quad*8];
            s[nt] = __builtin_amdgcn_mfma_f32_16x16x32_bf16(aq0, bk0, s[nt], 0,0,0);
            s[nt] = __builtin_amdgcn_mfma_f32_16x16x32_bf16(aq1, bk1, s[nt], 0,0,0);
        }
        const bool diag = (kt == qt);   // only the diagonal tile needs masking
        if (diag) {
#pragma unroll
            for (int nt = 0; nt < 4; nt++) {
                const int key = kt*64 + nt*16 + l15;
#pragma unroll
                for (int i = 0; i < 4; i++) {
                    const int qr = qt*64 + wave*16 + quad*4 + i;
                    if (key > qr) s[nt][i] = -INFINITY;
                }
            }
        }

        // online softmax (rows live across l15 lanes of the same quad)
        float alpha[4];
#pragma unroll
        for (int i = 0; i < 4; i++) {
            float v = fmaxf(fmaxf(s[0][i], s[1][i]), fmaxf(s[2][i], s[3][i]));
            v = fmaxf(v, __shfl_xor(v, 1));
            v = fmaxf(v, __shfl_xor(v, 2));
            v = fmaxf(v, __shfl_xor(v, 4));
            v = fmaxf(v, __shfl_xor(v, 8));
            const float mnew = fmaxf(m_run[i], v);   // finite (>=1 unmasked key)
            alpha[i] = __expf(m_run[i] - mnew);      // 0 on first tile
            m_run[i] = mnew;
        }
        float rs[4] = {0.f, 0.f, 0.f, 0.f};
#pragma unroll
        for (int nt = 0; nt < 4; nt++) {
#pragma unroll
            for (int i = 0; i < 4; i++) {
                const float p = __expf(s[nt][i] - m_run[i]);  // masked -> 0
                s[nt][i] = p;
                rs[i] += p;
            }
        }
#pragma unroll
        for (int i = 0; i < 4; i++) {
            float v = rs[i];
            v += __shfl_xor(v, 1);
            v += __shfl_xor(v, 2);
            v += __shfl_xor(v, 4);
            v += __shfl_xor(v, 8);
            l_run[i] = l_run[i] * alpha[i] + v;
        }
#pragma unroll
        for (int nt = 0; nt < 4; nt++)
#pragma unroll
            for (int i = 0; i < 4; i++) o[nt][i] *= alpha[i];

        // P: C-layout regs -> wave-private LDS -> A-layout frags (bf16)
#pragma unroll
        for (int nt = 0; nt < 4; nt++)
#pragma unroll
            for (int i = 0; i < 4; i++)
                pw[(quad*4 + i) * LSTR + nt*16 + l15] = f2bf(s[nt][i]);
        __threadfence_block();   // order LDS write -> read within the wave

        // O += P @ V   (contract over 64 keys = 2 mfma k-chunks)
#pragma unroll
        for (int c = 0; c < 2; c++) {
            short8 ap = *(const short8*)&pw[l15 * LSTR + c*32 + quad*8];
#pragma unroll
            for (int nt = 0; nt < 4; nt++) {
                short8 bv = *(const short8*)&Vs[(nt*16 + l15) * LSTR + c*32 + quad*8];
                o[nt] = __builtin_amdgcn_mfma_f32_16x16x32_bf16(ap, bv, o[nt], 0,0,0);
            }
        }
    }

    // epilogue: AO[b, t, h*64+d] = o / l
    const int h = bh & (HH - 1);
    const int b = bh >> 4;
#pragma unroll
    for (int nt = 0; nt < 4; nt++) {
#pragma unroll
        for (int i = 0; i < 4; i++) {
            const int t = qt*64 + wave*16 + quad*4 + i;
            const int e = h*64 + nt*16 + l15;
            AO[((long)(b*TT + t)) * EE + e] = f2bf(o[nt][i] / l_run[i]);
        }
    }
}

// ---------------------------------------------------------------------------
extern "C" void kernel_launch(void* const* d_in, const int* in_sizes, int n_in,
                              void* d_out, int out_size, void* d_ws, size_t ws_size,
                              hipStream_t stream)
{
    const void* query  = d_in[0];
    const void* key_in = d_in[1];
    const void* value  = d_in[2];
    // d_in[3] = mask (int32 tril) — causal is hard-coded in flash_kernel
    const void*  Wq = d_in[4];
    const float* bq = (const float*)d_in[5];
    const void*  Wk = d_in[6];
    const float* bk = (const float*)d_in[7];
    const void*  Wv = d_in[8];
    const float* bv = (const float*)d_in[9];
    const void*  Wo = d_in[10];
    const float* bo = (const float*)d_in[11];

    ushort* ws = (ushort*)d_ws;
    const size_t NPH = (size_t)BH * TT * DD;   // 8388608 elems per tensor
    ushort* Qh  = ws;                          // 16 MB  [bh][t][d], pre-scaled
    ushort* Kh  = ws + NPH;                    // 16 MB  [bh][t][d]
    ushort* Vth = ws + 2*NPH;                  // 16 MB  [bh][d][t]
    ushort* AO  = ws + 3*NPH;                  // 16 MB  [b][t][e]

    dim3 gemm_grid(EE/128, MM/128);           // 8 x 64
    gemm_nt<1,1,1><<<gemm_grid, 256, 0, stream>>>(query,  Wq, bq, Qh, 0.125f);
    gemm_nt<1,1,1><<<gemm_grid, 256, 0, stream>>>(key_in, Wk, bk, Kh, 1.0f);
    gemm_nt<1,1,2><<<gemm_grid, 256, 0, stream>>>(value,  Wv, bv, Vth, 1.0f);
    flash_kernel<<<dim3(TT/64, BH), 256, 0, stream>>>(Qh, Kh, Vth, AO);
    gemm_nt<0,1,0><<<gemm_grid, 256, 0, stream>>>(AO, Wo, bo, d_out, 1.0f);
}

// Round 5
// 520.914 us; speedup vs baseline: 1.6526x; 1.1769x over previous
//
#include <hip/hip_runtime.h>
#include <hip/hip_bf16.h>
#include <cstdint>

// Problem constants
#define BB 4
#define TT 2048
#define EE 1024
#define HH 16
#define DD 64
#define BH (BB*HH)       // 64
#define MM (BB*TT)       // 8192 rows for projection GEMMs
#define KK 1024          // contraction dim for projections
#define KSTR 72          // flash K-tile LDS row stride (ushorts)
#define VSTR 136         // flash V/P-tile LDS row stride (ushorts)

typedef __attribute__((ext_vector_type(8))) short short8;    // 8 x bf16
typedef __attribute__((ext_vector_type(4))) float float4_;   // MFMA accumulator
typedef __attribute__((ext_vector_type(4))) ushort ushort4_;

__device__ __forceinline__ void gl_lds16(const void* g, void* l) {
    __builtin_amdgcn_global_load_lds(
        (const __attribute__((address_space(1))) void*)g,
        (__attribute__((address_space(3))) void*)l, 16, 0, 0);
}

__device__ __forceinline__ ushort f2bf(float v) {
    __hip_bfloat16 h = __float2bfloat16(v);
    return *(ushort*)&h;
}

// ---------------------------------------------------------------------------
// NT GEMM: C[n,e] = sum_k A[n,k]*W[e,k] + bias[e], then *scale.
// fp32 operands: register-prefetched dwordx4 loads, cvt at STAGE time,
// ds_write_b128 -> inner loop reads are pure bf16 b128 (m97 path, no cvt).
// bf16 operands: global_load_lds width-16 (m97).
// MODE 0: C fp32 row-major [MM, EE]
// MODE 1: scatter bf16 per-head [B*H, T, D]
// MODE 2: scatter bf16 per-head transposed [B*H, D, T] (packed 8B stores)
// 128x128 tile, BK=32, 256 threads (4 waves, 2x2 of 64x64).
// ---------------------------------------------------------------------------
template<int AF32, int WF32, int MODE>
__global__ __launch_bounds__(256, 2) void gemm_nt(
    const void* __restrict__ A, const void* __restrict__ W,
    const float* __restrict__ bias, void* __restrict__ Cout, float scale)
{
    __shared__ __align__(16) ushort As[128*32];
    __shared__ __align__(16) ushort Bs[128*32];

    const int tid  = threadIdx.x;
    const int wave = tid >> 6;
    const int lane = tid & 63;
    const int l15  = lane & 15;
    const int quad = lane >> 4;
    const int wm   = wave & 1;   // row half
    const int wn   = wave >> 1;  // col half

    const long rowBase = (long)blockIdx.y * 128;
    const long colBase = (long)blockIdx.x * 128;

    // staging assignment (fp32 path): thread owns row r2, 16-float half hf
    const int r2 = tid >> 1, hf = tid & 1;

    float4_ apre[4], wpre[4];
    if (AF32) {
        const float* Af = (const float*)A;
#pragma unroll
        for (int j = 0; j < 4; j++)
            apre[j] = *(const float4_*)&Af[(rowBase + r2) * KK + hf*16 + j*4];
    }
    if (WF32) {
        const float* Wf = (const float*)W;
#pragma unroll
        for (int j = 0; j < 4; j++)
            wpre[j] = *(const float4_*)&Wf[(colBase + r2) * KK + hf*16 + j*4];
    }

    float4_ acc[4][4];
#pragma unroll
    for (int i = 0; i < 4; i++)
#pragma unroll
        for (int j = 0; j < 4; j++) acc[i][j] = float4_{0.f, 0.f, 0.f, 0.f};

    for (int k0 = 0; k0 < KK; k0 += 32) {
        // convert prefetched fp32 regs -> bf16 (before barrier; vmcnt waits here)
        short8 sa0, sa1, sw0, sw1;
        if (AF32) {
#pragma unroll
            for (int j = 0; j < 4; j++) {
                sa0[j] = (short)f2bf(apre[0][j]); sa0[4+j] = (short)f2bf(apre[1][j]);
                sa1[j] = (short)f2bf(apre[2][j]); sa1[4+j] = (short)f2bf(apre[3][j]);
            }
        }
        if (WF32) {
#pragma unroll
            for (int j = 0; j < 4; j++) {
                sw0[j] = (short)f2bf(wpre[0][j]); sw0[4+j] = (short)f2bf(wpre[1][j]);
                sw1[j] = (short)f2bf(wpre[2][j]); sw1[4+j] = (short)f2bf(wpre[3][j]);
            }
        }
        __syncthreads();   // previous iteration's LDS reads done
        if (AF32) {
            *(short8*)&As[r2*32 + hf*16]     = sa0;
            *(short8*)&As[r2*32 + hf*16 + 8] = sa1;
        } else {
            const ushort* Ab = (const ushort*)A;
#pragma unroll
            for (int it = 0; it < 2; it++) {
                int idx = it * 256 + tid;
                int r   = idx >> 2;
                int c8  = (idx & 3) * 8;
                gl_lds16(Ab + (rowBase + r) * KK + k0 + c8, &As[idx * 8]);
            }
        }
        if (WF32) {
            *(short8*)&Bs[r2*32 + hf*16]     = sw0;
            *(short8*)&Bs[r2*32 + hf*16 + 8] = sw1;
        } else {
            const ushort* Wb = (const ushort*)W;
#pragma unroll
            for (int it = 0; it < 2; it++) {
                int idx = it * 256 + tid;
                int r   = idx >> 2;
                int c8  = (idx & 3) * 8;
                gl_lds16(Wb + (colBase + r) * KK + k0 + c8, &Bs[idx * 8]);
            }
        }
        __syncthreads();

        // prefetch next k-step (overlaps with MFMA below)
        if (k0 + 32 < KK) {
            if (AF32) {
                const float* Af = (const float*)A;
#pragma unroll
                for (int j = 0; j < 4; j++)
                    apre[j] = *(const float4_*)&Af[(rowBase + r2) * KK + k0 + 32 + hf*16 + j*4];
            }
            if (WF32) {
                const float* Wf = (const float*)W;
#pragma unroll
                for (int j = 0; j < 4; j++)
                    wpre[j] = *(const float4_*)&Wf[(colBase + r2) * KK + k0 + 32 + hf*16 + j*4];
            }
        }

        short8 af[4], bf[4];
#pragma unroll
        for (int mt = 0; mt < 4; mt++)
            af[mt] = *(const short8*)&As[(wm*64 + mt*16 + l15) * 32 + quad*8];
#pragma unroll
        for (int nt = 0; nt < 4; nt++)
            bf[nt] = *(const short8*)&Bs[(wn*64 + nt*16 + l15) * 32 + quad*8];
#pragma unroll
        for (int mt = 0; mt < 4; mt++)
#pragma unroll
            for (int nt = 0; nt < 4; nt++)
                acc[mt][nt] = __builtin_amdgcn_mfma_f32_16x16x32_bf16(
                    af[mt], bf[nt], acc[mt][nt], 0, 0, 0);
    }

    // Epilogue: C/D layout col = lane&15, row = quad*4 + reg
#pragma unroll
    for (int nt = 0; nt < 4; nt++) {
        const long col = colBase + wn*64 + nt*16 + l15;
        const float bv = bias[col];
#pragma unroll
        for (int mt = 0; mt < 4; mt++) {
            const long row0 = rowBase + wm*64 + mt*16 + quad*4;
            if (MODE == 2) {
                const long h = col >> 6, d = col & (DD - 1);
                const long b = row0 >> 11, t0 = row0 & (TT - 1);
                ushort4_ pk;
#pragma unroll
                for (int i = 0; i < 4; i++) pk[i] = f2bf((acc[mt][nt][i] + bv) * scale);
                *(ushort4_*)((ushort*)Cout + ((b*HH + h)*DD + d)*TT + t0) = pk;
            } else {
#pragma unroll
                for (int i = 0; i < 4; i++) {
                    const long row = row0 + i;
                    const float v = (acc[mt][nt][i] + bv) * scale;
                    if (MODE == 0) {
                        ((float*)Cout)[row * EE + col] = v;
                    } else {
                        const long b = row >> 11, t = row & (TT - 1);
                        const long h = col >> 6,  d = col & (DD - 1);
                        ((ushort*)Cout)[(((b*HH + h) * TT) + t) * DD + d] = f2bf(v);
                    }
                }
            }
        }
    }
}

// ---------------------------------------------------------------------------
// Flash attention (causal). Q,K: [B*H, T, D] bf16; Vt: [B*H, D, T] bf16;
// AO: [B, T, E] bf16.  Scale pre-folded into Q.
// Block: 64 q-rows (wave w owns rows w*16..w*16+15), 128-KEY tiles,
// register-prefetched staging (next tile's loads overlap current compute).
// LDS strides 72/136 ushorts: bank-balanced b128 access.
// ---------------------------------------------------------------------------
__global__ __launch_bounds__(256, 3) void flash_kernel(
    const ushort* __restrict__ Qh, const ushort* __restrict__ Kh,
    const ushort* __restrict__ Vt, ushort* __restrict__ AO)
{
    __shared__ __align__(16) ushort Ks[128*KSTR];    // [key][d]     18.4 KB
    __shared__ __align__(16) ushort Vs[64*VSTR];     // [d][key]     17.4 KB
    __shared__ __align__(16) ushort Ps[4][16*VSTR];  // per-wave P   17.4 KB

    const int qt  = (TT/64 - 1) - blockIdx.x;  // heavy tiles dispatch first
    const int bh  = blockIdx.y;                // b*H + h
    const int tid = threadIdx.x;
    const int wave = tid >> 6, lane = tid & 63;
    const int l15 = lane & 15, quad = lane >> 4;

    const ushort* Qb = Qh + (long)bh * TT * DD;
    const ushort* Kb = Kh + (long)bh * TT * DD;
    const ushort* Vb = Vt + (long)bh * DD * TT;

    // Q A-fragments (A[m=lane&15][k=quad*8+j]), kept in registers
    const int qrowA = qt*64 + wave*16 + l15;
    short8 aq0 = *(const short8*)&Qb[(long)qrowA * DD + quad*8];
    short8 aq1 = *(const short8*)&Qb[(long)qrowA * DD + 32 + quad*8];

    float4_ o[4];
#pragma unroll
    for (int nt = 0; nt < 4; nt++) o[nt] = float4_{0.f, 0.f, 0.f, 0.f};
    float m_run[4], l_run[4];
#pragma unroll
    for (int i = 0; i < 4; i++) { m_run[i] = -INFINITY; l_run[i] = 0.0f; }

    ushort* pw = &Ps[wave][0];
    const int nkt = (qt*64 + 63) / 128 + 1;    // number of 128-key tiles

    // prefetch tile 0 into registers
    short8 kreg[4], vreg[4];
#pragma unroll
    for (int it = 0; it < 4; it++) {
        int c = it * 256 + tid;                    // 0..1023
        int kk = c >> 3, ks = c & 7;               // K: key, 16B seg
        kreg[it] = *(const short8*)&Kb[(long)kk * DD + ks*8];
        int dd = c >> 4, vs = c & 15;              // V: d, 16B seg
        vreg[it] = *(const short8*)&Vb[(long)dd * TT + vs*8];
    }

    for (int kt = 0; kt < nkt; kt++) {
        __syncthreads();   // previous tile's LDS reads done
#pragma unroll
        for (int it = 0; it < 4; it++) {
            int c = it * 256 + tid;
            int kk = c >> 3, ks = c & 7;
            *(short8*)&Ks[kk*KSTR + ks*8] = kreg[it];
            int dd = c >> 4, vs = c & 15;
            *(short8*)&Vs[dd*VSTR + vs*8] = vreg[it];
        }
        __syncthreads();

        // prefetch next tile (latency overlaps all compute below)
        if (kt + 1 < nkt) {
            const long koff = (long)(kt+1) * 128;
#pragma unroll
            for (int it = 0; it < 4; it++) {
                int c = it * 256 + tid;
                int kk = c >> 3, ks = c & 7;
                kreg[it] = *(const short8*)&Kb[(koff + kk) * DD + ks*8];
                int dd = c >> 4, vs = c & 15;
                vreg[it] = *(const short8*)&Vb[(long)dd * TT + koff + vs*8];
            }
        }

        // S = Q K^T over 128 keys  (C layout: row=quad*4+i, col=l15 per nt)
        float4_ s[8];
#pragma unroll
        for (int nt = 0; nt < 8; nt++) {
            s[nt] = float4_{0.f, 0.f, 0.f, 0.f};
            short8 bk0 = *(const short8*)&Ks[(nt*16 + l15) * KSTR + quad*8];
            short8 bk1 = *(const short8*)&Ks[(nt*16 + l15) * KSTR + 32 + quad*8];
            s[nt] = __builtin_amdgcn_mfma_f32_16x16x32_bf16(aq0, bk0, s[nt], 0,0,0);
            s[nt] = __builtin_amdgcn_mfma_f32_16x16x32_bf16(aq1, bk1, s[nt], 0,0,0);
        }
        if (kt == nkt - 1) {   // only the last tile can cross the diagonal
#pragma unroll
            for (int nt = 0; nt < 8; nt++) {
                const int key = kt*128 + nt*16 + l15;
#pragma unroll
                for (int i = 0; i < 4; i++) {
                    const int qr = qt*64 + wave*16 + quad*4 + i;
                    if (key > qr) s[nt][i] = -INFINITY;
                }
            }
        }

        // online softmax (row spans the 16 l15 lanes of this quad)
        float alpha[4];
#pragma unroll
        for (int i = 0; i < 4; i++) {
            float v = s[0][i];
#pragma unroll
            for (int nt = 1; nt < 8; nt++) v = fmaxf(v, s[nt][i]);
            v = fmaxf(v, __shfl_xor(v, 1));
            v = fmaxf(v, __shfl_xor(v, 2));
            v = fmaxf(v, __shfl_xor(v, 4));
            v = fmaxf(v, __shfl_xor(v, 8));
            const float mnew = fmaxf(m_run[i], v);   // finite (>=1 unmasked key)
            alpha[i] = __expf(m_run[i] - mnew);      // 0 on first tile
            m_run[i] = mnew;
        }
        float rs[4] = {0.f, 0.f, 0.f, 0.f};
#pragma unroll
        for (int nt = 0; nt < 8; nt++) {
#pragma unroll
            for (int i = 0; i < 4; i++) {
                const float p = __expf(s[nt][i] - m_run[i]);  // masked -> 0
                s[nt][i] = p;
                rs[i] += p;
            }
        }
#pragma unroll
        for (int i = 0; i < 4; i++) {
            float v = rs[i];
            v += __shfl_xor(v, 1);
            v += __shfl_xor(v, 2);
            v += __shfl_xor(v, 4);
            v += __shfl_xor(v, 8);
            l_run[i] = l_run[i] * alpha[i] + v;
        }
#pragma unroll
        for (int nt = 0; nt < 4; nt++)
#pragma unroll
            for (int i = 0; i < 4; i++) o[nt][i] *= alpha[i];

        // P: C-layout regs -> wave-private LDS -> A-layout frags (bf16)
#pragma unroll
        for (int nt = 0; nt < 8; nt++)
#pragma unroll
            for (int i = 0; i < 4; i++)
                pw[(quad*4 + i) * VSTR + nt*16 + l15] = f2bf(s[nt][i]);
        __threadfence_block();   // order LDS write -> read within the wave

        // O += P @ V   (contract over 128 keys = 4 mfma k-chunks)
#pragma unroll
        for (int c = 0; c < 4; c++) {
            short8 ap = *(const short8*)&pw[l15 * VSTR + c*32 + quad*8];
#pragma unroll
            for (int nt = 0; nt < 4; nt++) {
                short8 bv = *(const short8*)&Vs[(nt*16 + l15) * VSTR + c*32 + quad*8];
                o[nt] = __builtin_amdgcn_mfma_f32_16x16x32_bf16(ap, bv, o[nt], 0,0,0);
            }
        }
    }

    // epilogue: AO[b, t, h*64+d] = o / l
    const int h = bh & (HH - 1);
    const int b = bh >> 4;
#pragma unroll
    for (int nt = 0; nt < 4; nt++) {
#pragma unroll
        for (int i = 0; i < 4; i++) {
            const int t = qt*64 + wave*16 + quad*4 + i;
            const int e = h*64 + nt*16 + l15;
            AO[((long)(b*TT + t)) * EE + e] = f2bf(o[nt][i] / l_run[i]);
        }
    }
}

// ---------------------------------------------------------------------------
extern "C" void kernel_launch(void* const* d_in, const int* in_sizes, int n_in,
                              void* d_out, int out_size, void* d_ws, size_t ws_size,
                              hipStream_t stream)
{
    const void* query  = d_in[0];
    const void* key_in = d_in[1];
    const void* value  = d_in[2];
    // d_in[3] = mask (int32 tril) — causal is hard-coded in flash_kernel
    const void*  Wq = d_in[4];
    const float* bq = (const float*)d_in[5];
    const void*  Wk = d_in[6];
    const float* bk = (const float*)d_in[7];
    const void*  Wv = d_in[8];
    const float* bv = (const float*)d_in[9];
    const void*  Wo = d_in[10];
    const float* bo = (const float*)d_in[11];

    ushort* ws = (ushort*)d_ws;
    const size_t NPH = (size_t)BH * TT * DD;   // 8388608 elems per tensor
    ushort* Qh  = ws;                          // 16 MB  [bh][t][d], pre-scaled
    ushort* Kh  = ws + NPH;                    // 16 MB  [bh][t][d]
    ushort* Vth = ws + 2*NPH;                  // 16 MB  [bh][d][t]
    ushort* AO  = ws + 3*NPH;                  // 16 MB  [b][t][e]

    dim3 gemm_grid(EE/128, MM/128);           // 8 x 64
    gemm_nt<1,1,1><<<gemm_grid, 256, 0, stream>>>(query,  Wq, bq, Qh, 0.125f);
    gemm_nt<1,1,1><<<gemm_grid, 256, 0, stream>>>(key_in, Wk, bk, Kh, 1.0f);
    gemm_nt<1,1,2><<<gemm_grid, 256, 0, stream>>>(value,  Wv, bv, Vth, 1.0f);
    flash_kernel<<<dim3(TT/64, BH), 256, 0, stream>>>(Qh, Kh, Vth, AO);
    gemm_nt<0,1,0><<<gemm_grid, 256, 0, stream>>>(AO, Wo, bo, d_out, 1.0f);
}

// Round 6
// 470.613 us; speedup vs baseline: 1.8292x; 1.1069x over previous
//
#include <hip/hip_runtime.h>
#include <hip/hip_bf16.h>
#include <cstdint>

// Problem constants
#define BB 4
#define TT 2048
#define EE 1024
#define HH 16
#define DD 64
#define BH (BB*HH)       // 64
#define MM (BB*TT)       // 8192 rows for projection GEMMs
#define KK 1024          // contraction dim for projections
#define KSTR 72          // flash K-tile LDS row stride (ushorts)
#define VSTR 136         // flash V/P-tile LDS row stride (ushorts)
#define LOG2E 1.44269504088896340736f

typedef __attribute__((ext_vector_type(8))) short short8;    // 8 x bf16
typedef __attribute__((ext_vector_type(4))) float float4_;   // MFMA accumulator
typedef __attribute__((ext_vector_type(4))) ushort ushort4_;

__device__ __forceinline__ void gl_lds16(const void* g, void* l) {
    __builtin_amdgcn_global_load_lds(
        (const __attribute__((address_space(1))) void*)g,
        (__attribute__((address_space(3))) void*)l, 16, 0, 0);
}

__device__ __forceinline__ ushort f2bf(float v) {
    __hip_bfloat16 h = __float2bfloat16(v);
    return *(ushort*)&h;
}

// ---------------------------------------------------------------------------
// fp32 -> bf16 conversion. grid.y selects segment (ptr,n); oversized grid.x
// blocks for short segments exit early.
// ---------------------------------------------------------------------------
__global__ __launch_bounds__(256) void cvt_kernel(
    const float* __restrict__ s0, ushort* __restrict__ d0, int n0,
    const float* __restrict__ s1, ushort* __restrict__ d1, int n1,
    const float* __restrict__ s2, ushort* __restrict__ d2, int n2,
    const float* __restrict__ s3, ushort* __restrict__ d3, int n3)
{
    const float* s; ushort* d; int n;
    switch (blockIdx.y) {
        case 0: s = s0; d = d0; n = n0; break;
        case 1: s = s1; d = d1; n = n1; break;
        case 2: s = s2; d = d2; n = n2; break;
        default: s = s3; d = d3; n = n3; break;
    }
    int i = (blockIdx.x * 256 + threadIdx.x) * 4;
    if (i >= n) return;
    float4_ v = *(const float4_*)&s[i];
    ushort4_ o;
#pragma unroll
    for (int j = 0; j < 4; j++) o[j] = f2bf(v[j]);
    *(ushort4_*)&d[i] = o;
}

// ---------------------------------------------------------------------------
// Pure-bf16 NT GEMM (m97 structure): C[n,e] = (sum_k A[n,k]*W[e,k] + bias[e])*scale
// MODE 0: C fp32 row-major [MM, EE]
// MODE 1: scatter bf16 per-head [B*H, T, D]
// MODE 2: scatter bf16 per-head transposed [B*H, D, T] (packed 8B stores)
// 128x128 tile, BK=32, 256 threads (4 waves, 2x2 of 64x64).
// ---------------------------------------------------------------------------
template<int MODE>
__global__ __launch_bounds__(256, 3) void gemm_nt(
    const ushort* __restrict__ A, const ushort* __restrict__ W,
    const float* __restrict__ bias, void* __restrict__ Cout, float scale)
{
    __shared__ __align__(16) ushort As[128*32];
    __shared__ __align__(16) ushort Bs[128*32];

    const int tid  = threadIdx.x;
    const int wave = tid >> 6;
    const int lane = tid & 63;
    const int l15  = lane & 15;
    const int quad = lane >> 4;
    const int wm   = wave & 1;   // row half
    const int wn   = wave >> 1;  // col half

    const long rowBase = (long)blockIdx.y * 128;
    const long colBase = (long)blockIdx.x * 128;

    float4_ acc[4][4];
#pragma unroll
    for (int i = 0; i < 4; i++)
#pragma unroll
        for (int j = 0; j < 4; j++) acc[i][j] = float4_{0.f, 0.f, 0.f, 0.f};

    for (int k0 = 0; k0 < KK; k0 += 32) {
        __syncthreads();
#pragma unroll
        for (int it = 0; it < 2; it++) {
            int idx = it * 256 + tid;          // 0..511
            int r   = idx >> 2;                // tile row 0..127
            int c8  = (idx & 3) * 8;           // k chunk (8 bf16 = 16B)
            gl_lds16(A + (rowBase + r) * KK + k0 + c8, &As[idx * 8]);
            gl_lds16(W + (colBase + r) * KK + k0 + c8, &Bs[idx * 8]);
        }
        __syncthreads();

        short8 af[4], bf[4];
#pragma unroll
        for (int mt = 0; mt < 4; mt++)
            af[mt] = *(const short8*)&As[(wm*64 + mt*16 + l15) * 32 + quad*8];
#pragma unroll
        for (int nt = 0; nt < 4; nt++)
            bf[nt] = *(const short8*)&Bs[(wn*64 + nt*16 + l15) * 32 + quad*8];
#pragma unroll
        for (int mt = 0; mt < 4; mt++)
#pragma unroll
            for (int nt = 0; nt < 4; nt++)
                acc[mt][nt] = __builtin_amdgcn_mfma_f32_16x16x32_bf16(
                    af[mt], bf[nt], acc[mt][nt], 0, 0, 0);
    }

    // Epilogue: C/D layout col = lane&15, row = quad*4 + reg
#pragma unroll
    for (int nt = 0; nt < 4; nt++) {
        const long col = colBase + wn*64 + nt*16 + l15;
        const float bv = bias[col];
#pragma unroll
        for (int mt = 0; mt < 4; mt++) {
            const long row0 = rowBase + wm*64 + mt*16 + quad*4;
            if (MODE == 2) {
                const long h = col >> 6, d = col & (DD - 1);
                const long b = row0 >> 11, t0 = row0 & (TT - 1);
                ushort4_ pk;
#pragma unroll
                for (int i = 0; i < 4; i++) pk[i] = f2bf((acc[mt][nt][i] + bv) * scale);
                *(ushort4_*)((ushort*)Cout + ((b*HH + h)*DD + d)*TT + t0) = pk;
            } else {
#pragma unroll
                for (int i = 0; i < 4; i++) {
                    const long row = row0 + i;
                    const float v = (acc[mt][nt][i] + bv) * scale;
                    if (MODE == 0) {
                        ((float*)Cout)[row * EE + col] = v;
                    } else {
                        const long b = row >> 11, t = row & (TT - 1);
                        const long h = col >> 6,  d = col & (DD - 1);
                        ((ushort*)Cout)[(((b*HH + h) * TT) + t) * DD + d] = f2bf(v);
                    }
                }
            }
        }
    }
}

// ---------------------------------------------------------------------------
// Flash attention (causal). Q,K: [B*H, T, D] bf16; Vt: [B*H, D, T] bf16;
// AO: [B, T, E] bf16.  Q pre-scaled by 0.125*log2(e) -> softmax via exp2.
// Block: 512 threads (8 waves) x 128 q-rows; 128-key tiles; register-
// prefetched staging (next tile's loads overlap current compute).
// LDS strides 72/136 ushorts: bank-balanced b128 access.  ~70.7 KB -> 2 blk/CU.
// ---------------------------------------------------------------------------
__global__ __launch_bounds__(512, 4) void flash_kernel(
    const ushort* __restrict__ Qh, const ushort* __restrict__ Kh,
    const ushort* __restrict__ Vt, ushort* __restrict__ AO)
{
    __shared__ __align__(16) ushort Ks[128*KSTR];    // [key][d]     18.4 KB
    __shared__ __align__(16) ushort Vs[64*VSTR];     // [d][key]     17.4 KB
    __shared__ __align__(16) ushort Ps[8][16*VSTR];  // per-wave P   34.8 KB

    const int qt  = (TT/128 - 1) - blockIdx.x;  // heavy tiles dispatch first
    const int bh  = blockIdx.y;                 // b*H + h
    const int tid = threadIdx.x;
    const int wave = tid >> 6, lane = tid & 63;
    const int l15 = lane & 15, quad = lane >> 4;

    const ushort* Qb = Qh + (long)bh * TT * DD;
    const ushort* Kb = Kh + (long)bh * TT * DD;
    const ushort* Vb = Vt + (long)bh * DD * TT;

    // Q A-fragments (A[m=lane&15][k=quad*8+j]), kept in registers
    const int qrowA = qt*128 + wave*16 + l15;
    short8 aq0 = *(const short8*)&Qb[(long)qrowA * DD + quad*8];
    short8 aq1 = *(const short8*)&Qb[(long)qrowA * DD + 32 + quad*8];

    float4_ o[4];
#pragma unroll
    for (int nt = 0; nt < 4; nt++) o[nt] = float4_{0.f, 0.f, 0.f, 0.f};
    float m_run[4], l_run[4];
#pragma unroll
    for (int i = 0; i < 4; i++) { m_run[i] = -INFINITY; l_run[i] = 0.0f; }

    ushort* pw = &Ps[wave][0];
    const int nkt = qt + 1;                    // number of 128-key tiles

    // prefetch tile 0 into registers (K: 128x64, V^T: 64x128)
    short8 kreg[2], vreg[2];
#pragma unroll
    for (int it = 0; it < 2; it++) {
        int c = it * 512 + tid;                    // 0..1023
        int kk = c >> 3, ks = c & 7;               // K: key, 16B seg
        kreg[it] = *(const short8*)&Kb[(long)kk * DD + ks*8];
        int dd = c >> 4, vs = c & 15;              // V: d, 16B seg
        vreg[it] = *(const short8*)&Vb[(long)dd * TT + vs*8];
    }

    for (int kt = 0; kt < nkt; kt++) {
        __syncthreads();   // previous tile's LDS reads done
#pragma unroll
        for (int it = 0; it < 2; it++) {
            int c = it * 512 + tid;
            int kk = c >> 3, ks = c & 7;
            *(short8*)&Ks[kk*KSTR + ks*8] = kreg[it];
            int dd = c >> 4, vs = c & 15;
            *(short8*)&Vs[dd*VSTR + vs*8] = vreg[it];
        }
        __syncthreads();

        // prefetch next tile (latency overlaps all compute below)
        if (kt + 1 < nkt) {
            const long koff = (long)(kt+1) * 128;
#pragma unroll
            for (int it = 0; it < 2; it++) {
                int c = it * 512 + tid;
                int kk = c >> 3, ks = c & 7;
                kreg[it] = *(const short8*)&Kb[(koff + kk) * DD + ks*8];
                int dd = c >> 4, vs = c & 15;
                vreg[it] = *(const short8*)&Vb[(long)dd * TT + koff + vs*8];
            }
        }

        // S = Q K^T over 128 keys (log2 domain; C layout row=quad*4+i col=l15)
        float4_ s[8];
#pragma unroll
        for (int nt = 0; nt < 8; nt++) {
            s[nt] = float4_{0.f, 0.f, 0.f, 0.f};
            short8 bk0 = *(const short8*)&Ks[(nt*16 + l15) * KSTR + quad*8];
            short8 bk1 = *(const short8*)&Ks[(nt*16 + l15) * KSTR + 32 + quad*8];
            s[nt] = __builtin_amdgcn_mfma_f32_16x16x32_bf16(aq0, bk0, s[nt], 0,0,0);
            s[nt] = __builtin_amdgcn_mfma_f32_16x16x32_bf16(aq1, bk1, s[nt], 0,0,0);
        }
        if (kt == nkt - 1) {   // only the diagonal tile crosses the mask
#pragma unroll
            for (int nt = 0; nt < 8; nt++) {
                const int key = kt*128 + nt*16 + l15;
#pragma unroll
                for (int i = 0; i < 4; i++) {
                    const int qr = qt*128 + wave*16 + quad*4 + i;
                    if (key > qr) s[nt][i] = -INFINITY;
                }
            }
        }

        // online softmax in log2 domain (row spans 16 l15 lanes of this quad)
        float alpha[4];
#pragma unroll
        for (int i = 0; i < 4; i++) {
            float v = s[0][i];
#pragma unroll
            for (int nt = 1; nt < 8; nt++) v = fmaxf(v, s[nt][i]);
            v = fmaxf(v, __shfl_xor(v, 1));
            v = fmaxf(v, __shfl_xor(v, 2));
            v = fmaxf(v, __shfl_xor(v, 4));
            v = fmaxf(v, __shfl_xor(v, 8));
            const float mnew = fmaxf(m_run[i], v);   // finite (>=1 unmasked key)
            alpha[i] = exp2f(m_run[i] - mnew);       // 0 on first tile
            m_run[i] = mnew;
        }
        float rs[4] = {0.f, 0.f, 0.f, 0.f};
#pragma unroll
        for (int nt = 0; nt < 8; nt++) {
#pragma unroll
            for (int i = 0; i < 4; i++) {
                const float p = exp2f(s[nt][i] - m_run[i]);  // masked -> 0
                s[nt][i] = p;
                rs[i] += p;
            }
        }
#pragma unroll
        for (int i = 0; i < 4; i++) {
            float v = rs[i];
            v += __shfl_xor(v, 1);
            v += __shfl_xor(v, 2);
            v += __shfl_xor(v, 4);
            v += __shfl_xor(v, 8);
            l_run[i] = l_run[i] * alpha[i] + v;
        }
#pragma unroll
        for (int nt = 0; nt < 4; nt++)
#pragma unroll
            for (int i = 0; i < 4; i++) o[nt][i] *= alpha[i];

        // P: C-layout regs -> wave-private LDS -> A-layout frags (bf16)
#pragma unroll
        for (int nt = 0; nt < 8; nt++)
#pragma unroll
            for (int i = 0; i < 4; i++)
                pw[(quad*4 + i) * VSTR + nt*16 + l15] = f2bf(s[nt][i]);
        __threadfence_block();   // order LDS write -> read within the wave

        // O += P @ V   (contract over 128 keys = 4 mfma k-chunks)
#pragma unroll
        for (int c = 0; c < 4; c++) {
            short8 ap = *(const short8*)&pw[l15 * VSTR + c*32 + quad*8];
#pragma unroll
            for (int nt = 0; nt < 4; nt++) {
                short8 bv = *(const short8*)&Vs[(nt*16 + l15) * VSTR + c*32 + quad*8];
                o[nt] = __builtin_amdgcn_mfma_f32_16x16x32_bf16(ap, bv, o[nt], 0,0,0);
            }
        }
    }

    // epilogue: AO[b, t, h*64+d] = o / l
    const int h = bh & (HH - 1);
    const int b = bh >> 4;
#pragma unroll
    for (int nt = 0; nt < 4; nt++) {
#pragma unroll
        for (int i = 0; i < 4; i++) {
            const int t = qt*128 + wave*16 + quad*4 + i;
            const int e = h*64 + nt*16 + l15;
            AO[((long)(b*TT + t)) * EE + e] = f2bf(o[nt][i] / l_run[i]);
        }
    }
}

// ---------------------------------------------------------------------------
extern "C" void kernel_launch(void* const* d_in, const int* in_sizes, int n_in,
                              void* d_out, int out_size, void* d_ws, size_t ws_size,
                              hipStream_t stream)
{
    const float* query  = (const float*)d_in[0];
    const float* key_in = (const float*)d_in[1];
    const float* value  = (const float*)d_in[2];
    // d_in[3] = mask (int32 tril) — causal is hard-coded in flash_kernel
    const float* Wq = (const float*)d_in[4];
    const float* bq = (const float*)d_in[5];
    const float* Wk = (const float*)d_in[6];
    const float* bk = (const float*)d_in[7];
    const float* Wv = (const float*)d_in[8];
    const float* bv = (const float*)d_in[9];
    const float* Wo = (const float*)d_in[10];
    const float* bo = (const float*)d_in[11];

    ushort* ws = (ushort*)d_ws;
    const size_t NIN = (size_t)MM * KK;        // 8,388,608 elems (inputs)
    const size_t NW  = (size_t)EE * KK;        // 1,048,576 elems (weights)
    ushort* X0  = ws;                          // 16 MB cvt scratch (Q/K/V serially)
    ushort* Wqc = ws + NIN;                    // 2 MB
    ushort* Wkc = Wqc + NW;
    ushort* Wvc = Wkc + NW;
    ushort* Woc = Wvc + NW;
    ushort* Qh  = Woc + NW;                    // 16 MB  [bh][t][d], pre-scaled
    ushort* Kh  = Qh + NIN;                    // 16 MB  [bh][t][d]
    ushort* Vth = Kh + NIN;                    // 16 MB  [bh][d][t]
    ushort* AO  = X0;                          // alias: X0 dead after gemmV

    dim3 gemm_grid(EE/128, MM/128);            // 8 x 64
    const dim3 cvtW_grid(NW/1024, 4), cvtI_grid(NIN/1024, 1);

    // weights -> bf16 (batched)
    cvt_kernel<<<cvtW_grid, 256, 0, stream>>>(Wq, Wqc, (int)NW, Wk, Wkc, (int)NW,
                                              Wv, Wvc, (int)NW, Wo, Woc, (int)NW);
    // Q/K/V: cvt then project (X0 reused; stream order serializes correctly)
    cvt_kernel<<<cvtI_grid, 256, 0, stream>>>(query, X0, (int)NIN, nullptr, nullptr, 0,
                                              nullptr, nullptr, 0, nullptr, nullptr, 0);
    gemm_nt<1><<<gemm_grid, 256, 0, stream>>>(X0, Wqc, bq, Qh, 0.125f * LOG2E);
    cvt_kernel<<<cvtI_grid, 256, 0, stream>>>(key_in, X0, (int)NIN, nullptr, nullptr, 0,
                                              nullptr, nullptr, 0, nullptr, nullptr, 0);
    gemm_nt<1><<<gemm_grid, 256, 0, stream>>>(X0, Wkc, bk, Kh, 1.0f);
    cvt_kernel<<<cvtI_grid, 256, 0, stream>>>(value, X0, (int)NIN, nullptr, nullptr, 0,
                                              nullptr, nullptr, 0, nullptr, nullptr, 0);
    gemm_nt<2><<<gemm_grid, 256, 0, stream>>>(X0, Wvc, bv, Vth, 1.0f);

    flash_kernel<<<dim3(TT/128, BH), 512, 0, stream>>>(Qh, Kh, Vth, AO);
    gemm_nt<0><<<gemm_grid, 256, 0, stream>>>(AO, Woc, bo, d_out, 1.0f);
}